// Round 1
// baseline (1183.684 us; speedup 1.0000x reference)
//
#include <hip/hip_runtime.h>
#include <hip/hip_bf16.h>

// BS=16384, D=100, H=16, P=2
// inputs: x(BS,100) M(BS,100,100) W0(100,16,100) W1(100,16,16) W2(100,2,16)
//         b0(100,16) b1(100,16) b2(100,2)   all f32
// out: (BS,100,2) f32

typedef __attribute__((ext_vector_type(8))) short short8v;
typedef __attribute__((ext_vector_type(4))) short short4v;
typedef __attribute__((ext_vector_type(4))) float float4v;

#define MFMA(a,b,c) __builtin_amdgcn_mfma_f32_16x16x32_bf16((a),(b),(c),0,0,0)

__device__ __forceinline__ ushort f2bf(float v){
  __hip_bfloat16 b = __float2bfloat16(v);      // RNE
  ushort u; __builtin_memcpy(&u, &b, 2); return u;
}
__device__ __forceinline__ float bf2f(ushort u){
  unsigned x = ((unsigned)u) << 16; float f; __builtin_memcpy(&f, &x, 4); return f;
}
__device__ __forceinline__ void split_bf(float v, ushort &hi, ushort &lo){
  hi = f2bf(v);
  lo = f2bf(v - bf2f(hi));                     // hi+lo carries ~16 mantissa bits
}

// ---------------- weight packing into ws (ushort elements) ----------------
//  W0hi [100][4][64][8] @ 0        (204800 ushorts)
//  W0lo                 @ 204800
//  W1hi [100][64][8]    @ 409600   (51200)
//  W1lo                 @ 460800
//  W2hi [100][64][8]    @ 512000
//  W2lo                 @ 563200    total 614400 ushorts = 1,228,800 B
// Fragment convention (16x16x32 bf16): lane l -> col/row = l&15, k = (l>>4)*8+e.
__global__ void pack_weights(const float* __restrict__ W0, const float* __restrict__ W1,
                             const float* __restrict__ W2, ushort* __restrict__ ws)
{
  int s = blockIdx.x*256 + threadIdx.x;        // 0..38399
  int l = s & 63;
  int i = l & 15;
  int kb = (l >> 4) * 8;
  ushort hi[8], lo[8];
  ushort *dhi, *dlo;
  if (s < 25600){                              // W0: [t][c][lane]
    int t = s >> 8, c = (s >> 6) & 3;
#pragma unroll
    for (int e=0;e<8;++e){
      int j = c*32 + kb + e;
      float v = (j < 100) ? W0[t*1600 + i*100 + j] : 0.f;
      split_bf(v, hi[e], lo[e]);
    }
    dhi = ws + (size_t)s*8; dlo = ws + 204800 + (size_t)s*8;
  } else if (s < 32000){                       // W1: [t][lane], K padded 16->32 w/ zeros
    int s2 = s - 25600, t = s2 >> 6;
#pragma unroll
    for (int e=0;e<8;++e){
      int k = kb + e;
      float v = (k < 16) ? W1[t*256 + i*16 + k] : 0.f;
      split_bf(v, hi[e], lo[e]);
    }
    dhi = ws + 409600 + (size_t)s2*8; dlo = ws + 460800 + (size_t)s2*8;
  } else {                                     // W2: cols p<2 valid, rest zero
    int s2 = s - 32000, t = s2 >> 6;
#pragma unroll
    for (int e=0;e<8;++e){
      int k = kb + e;
      float v = (i < 2 && k < 16) ? W2[t*32 + i*16 + k] : 0.f;
      split_bf(v, hi[e], lo[e]);
    }
    dhi = ws + 512000 + (size_t)s2*8; dlo = ws + 563200 + (size_t)s2*8;
  }
  short8v vh, vl;
#pragma unroll
  for (int e=0;e<8;++e){ vh[e] = (short)hi[e]; vl[e] = (short)lo[e]; }
  *reinterpret_cast<short8v*>(dhi) = vh;
  *reinterpret_cast<short8v*>(dlo) = vl;
}

// ---------------- fused main kernel ----------------
// block: 16 batches x TCNT vars (t-quarter), 512 threads (8 waves).
// mxT layout (per t-local plane of 516 ushorts = 1032 B, odd-dword stride to
// spread staging-write banks): elem for MFMA lane L, e  at  t*516 + L*8 + e.
template<int TCNT>
__device__ __forceinline__ void run_block(
    const float* __restrict__ xg, const float* __restrict__ Mg,
    const float* __restrict__ b0g, const float* __restrict__ b1g,
    const float* __restrict__ b2g,
    const ushort* __restrict__ ws, float* __restrict__ outp,
    int bbase, int t0, float* x_lds, ushort* mxThi, ushort* mxTlo)
{
  const int tid  = threadIdx.x;
  const int lane = tid & 63;
  const int wave = tid >> 6;

  // x slab (16 x 100 f32), coalesced
  for (int idx = tid; idx < 1600; idx += 512)
    x_lds[idx] = xg[bbase*100 + idx];

  // wave -> t-slot assignment
  int cnt, tstart;
  if (TCNT == 28){ cnt = (wave < 4) ? 4 : 3; tstart = (wave < 4) ? wave*4 : 16 + (wave-4)*3; }
  else           { cnt = 3;                  tstart = wave*3; }

  const float4v z4 = {0.f,0.f,0.f,0.f};
  float4v acc[4];
#pragma unroll
  for (int ti=0; ti<4; ++ti) acc[ti] = z4;

  const ushort* W0hi = ws;
  const ushort* W0lo = ws + 204800;

  __syncthreads();

  for (int c=0; c<4; ++c){                     // j-chunks of 32 (j padded 100->128)
    // ---- stage g = M[b,j,t]*x[b,j]*(j!=t) as bf16 hi/lo, fragment-major ----
#pragma unroll
    for (int k=0; k<TCNT/2; ++k){
      int v  = k*512 + tid;                    // pair index over 16b x 32j x TCNT t
      int b  = v / (16*TCNT);
      int r  = v - b*(16*TCNT);
      int jl = r / (TCNT/2);
      int tl = (r - jl*(TCNT/2))*2;
      int j_abs = c*32 + jl;
      float2 mv = make_float2(0.f, 0.f);
      if (j_abs < 100)
        mv = *reinterpret_cast<const float2*>(Mg + (size_t)(bbase+b)*10000 + j_abs*100 + t0 + tl);
      float xv = x_lds[b*100 + (j_abs < 100 ? j_abs : 0)];
      int slot = ((jl>>3)<<4) | b;             // MFMA lane owning (b, jl)
      int base = tl*516 + slot*8 + (jl&7);
      {
        float g = (j_abs == t0+tl) ? 0.f : mv.x*xv;
        ushort h,l2; split_bf(g,h,l2);
        mxThi[base] = h; mxTlo[base] = l2;
      }
      {
        float g = (j_abs == t0+tl+1) ? 0.f : mv.y*xv;
        ushort h,l2; split_bf(g,h,l2);
        mxThi[base+516] = h; mxTlo[base+516] = l2;
      }
    }
    __syncthreads();
    // ---- layer-0 MFMA: C[b][i] += sum_j g[b][j] * W0[t][i][j] (3-term split) ----
#pragma unroll
    for (int ti=0; ti<4; ++ti){
      if (ti < cnt){
        int tloc = tstart + ti;
        int t_abs = t0 + tloc;
        const short4v* pa = reinterpret_cast<const short4v*>(mxThi + tloc*516 + lane*8);
        const short4v* pl = reinterpret_cast<const short4v*>(mxTlo + tloc*516 + lane*8);
        short8v ahi = __builtin_shufflevector(pa[0], pa[1], 0,1,2,3,4,5,6,7);
        short8v alo = __builtin_shufflevector(pl[0], pl[1], 0,1,2,3,4,5,6,7);
        short8v bhi = *reinterpret_cast<const short8v*>(W0hi + ((size_t)(t_abs*4 + c)*64 + lane)*8);
        short8v blo = *reinterpret_cast<const short8v*>(W0lo + ((size_t)(t_abs*4 + c)*64 + lane)*8);
        acc[ti] = MFMA(ahi, bhi, acc[ti]);
        acc[ti] = MFMA(alo, bhi, acc[ti]);
        acc[ti] = MFMA(ahi, blo, acc[ti]);
      }
    }
    __syncthreads();                           // protects next chunk's overwrite
  }

  // ---- layers 1 & 2 : per-wave private scratch aliased onto mxThi ----
  const ushort* W1hi = ws + 409600;
  const ushort* W1lo = ws + 460800;
  const ushort* W2hi = ws + 512000;
  const ushort* W2lo = ws + 563200;
  ushort* sHi = mxThi + wave*1024;             // 64 slots x 8 ushorts
  ushort* sLo = sHi + 512;
  {
    short8v zer = {0,0,0,0,0,0,0,0};           // zero k>=16 A-slots (avoid NaN*0)
    if (lane < 32) *reinterpret_cast<short8v*>(sHi + (32+lane)*8) = zer;
    else           *reinterpret_cast<short8v*>(sLo + lane*8)      = zer;
  }
  const int i16 = lane & 15;                   // C col = i
  const int qb  = (lane >> 4) * 4;             // C row base = b
  const int slotbase = (((i16>>3)<<4) | qb)*8 + (i16 & 7);

#pragma unroll
  for (int ti=0; ti<4; ++ti){
    if (ti < cnt){
      int t_abs = t0 + tstart + ti;
      float bias0 = b0g[t_abs*16 + i16];
      // transpose-write lrelu(h)+split into scratch: A[row=b][k=j]
#pragma unroll
      for (int r=0;r<4;++r){
        float vv = acc[ti][r] + bias0;
        vv = (vv > 0.f) ? vv : 0.01f*vv;
        ushort h,l2; split_bf(vv,h,l2);
        sHi[slotbase + r*8] = h; sLo[slotbase + r*8] = l2;
      }
      asm volatile("s_waitcnt lgkmcnt(0)" ::: "memory");
      float4v acc2 = z4;
      {
        short8v ahi = *reinterpret_cast<const short8v*>(sHi + lane*8);
        short8v alo = *reinterpret_cast<const short8v*>(sLo + lane*8);
        short8v bhi = *reinterpret_cast<const short8v*>(W1hi + ((size_t)t_abs*64 + lane)*8);
        short8v blo = *reinterpret_cast<const short8v*>(W1lo + ((size_t)t_abs*64 + lane)*8);
        acc2 = MFMA(ahi, bhi, acc2);
        acc2 = MFMA(alo, bhi, acc2);
        acc2 = MFMA(ahi, blo, acc2);
      }
      float bias1 = b1g[t_abs*16 + i16];
#pragma unroll
      for (int r=0;r<4;++r){
        float vv = acc2[r] + bias1;
        vv = (vv > 0.f) ? vv : 0.01f*vv;
        ushort h,l2; split_bf(vv,h,l2);
        sHi[slotbase + r*8] = h; sLo[slotbase + r*8] = l2;
      }
      asm volatile("s_waitcnt lgkmcnt(0)" ::: "memory");
      float4v acc3 = z4;
      {
        short8v ahi = *reinterpret_cast<const short8v*>(sHi + lane*8);
        short8v alo = *reinterpret_cast<const short8v*>(sLo + lane*8);
        short8v bhi = *reinterpret_cast<const short8v*>(W2hi + ((size_t)t_abs*64 + lane)*8);
        short8v blo = *reinterpret_cast<const short8v*>(W2lo + ((size_t)t_abs*64 + lane)*8);
        acc3 = MFMA(ahi, bhi, acc3);
        acc3 = MFMA(alo, bhi, acc3);
        acc3 = MFMA(ahi, blo, acc3);
      }
      if (i16 < 2){
        float bias2 = b2g[t_abs*2 + i16];
#pragma unroll
        for (int r=0;r<4;++r)
          outp[(size_t)(bbase + qb + r)*200 + t_abs*2 + i16] = acc3[r] + bias2;
      }
    }
  }
}

__global__ __launch_bounds__(512, 4)
void fused_kernel(const float* __restrict__ x, const float* __restrict__ M,
                  const float* __restrict__ b0, const float* __restrict__ b1,
                  const float* __restrict__ b2,
                  const ushort* __restrict__ ws, float* __restrict__ out)
{
  __shared__ float x_lds[1600];
  __shared__ __align__(16) ushort mxThi[28*516];   // 28,896 B
  __shared__ __align__(16) ushort mxTlo[28*516];   // total LDS 64,192 B
  int bt = blockIdx.x >> 2, tq = blockIdx.x & 3;
  int bbase = bt * 16;
  if (tq == 0)
    run_block<28>(x, M, b0, b1, b2, ws, out, bbase, 0,          x_lds, mxThi, mxTlo);
  else
    run_block<24>(x, M, b0, b1, b2, ws, out, bbase, 4 + 24*tq,  x_lds, mxThi, mxTlo);
}

extern "C" void kernel_launch(void* const* d_in, const int* in_sizes, int n_in,
                              void* d_out, int out_size, void* d_ws, size_t ws_size,
                              hipStream_t stream)
{
  const float* x  = (const float*)d_in[0];
  const float* M  = (const float*)d_in[1];
  const float* W0 = (const float*)d_in[2];
  const float* W1 = (const float*)d_in[3];
  const float* W2 = (const float*)d_in[4];
  const float* b0 = (const float*)d_in[5];
  const float* b1 = (const float*)d_in[6];
  const float* b2 = (const float*)d_in[7];
  ushort* ws = (ushort*)d_ws;                  // needs 1,228,800 B
  float* out = (float*)d_out;
  if (ws_size < 1228800) return;               // loud failure rather than corruption

  pack_weights<<<150, 256, 0, stream>>>(W0, W1, W2, ws);
  fused_kernel<<<4096, 512, 0, stream>>>(x, M, b0, b1, b2, ws, out);
}